// Round 2
// baseline (371.001 us; speedup 1.0000x reference)
//
#include <hip/hip_runtime.h>
#include <stdint.h>
#include <math.h>

typedef unsigned short u16;
typedef __attribute__((ext_vector_type(4))) float f32x4;
typedef __attribute__((ext_vector_type(4))) int i32x4;
typedef __attribute__((ext_vector_type(8))) short bf16x8;

__device__ __forceinline__ u16 f2bf(float f) {
  uint32_t u = __float_as_uint(f);
  u += 0x7FFFu + ((u >> 16) & 1u);
  return (u16)(u >> 16);
}

__device__ __forceinline__ void async16(const void* g, void* l) {
  __builtin_amdgcn_global_load_lds(
      (const __attribute__((address_space(1))) void*)g,
      (__attribute__((address_space(3))) void*)l, 16, 0, 0);
}

// ---------------- prep ----------------
__global__ void absmax_x(const float4* __restrict__ x, unsigned* __restrict__ amax, int n4) {
  int i = blockIdx.x * 256 + threadIdx.x;
  float m = 0.f;
  for (; i < n4; i += gridDim.x * 256) {
    float4 v = x[i];
    m = fmaxf(m, fmaxf(fmaxf(fabsf(v.x), fabsf(v.y)), fmaxf(fabsf(v.z), fabsf(v.w))));
  }
#pragma unroll
  for (int s = 1; s < 64; s <<= 1) m = fmaxf(m, __shfl_xor(m, s));
  if ((threadIdx.x & 63) == 0) atomicMax(amax, __float_as_uint(m));
}

__global__ void quant_x(const float4* __restrict__ x, char4* __restrict__ o,
                        const unsigned* __restrict__ amax, int n4) {
  int i = blockIdx.x * 256 + threadIdx.x;
  if (i >= n4) return;
  const float inv = 127.0f / __uint_as_float(amax[0]);
  float4 v = x[i];
  char4 r;
  r.x = (char)__float2int_rn(v.x * inv);
  r.y = (char)__float2int_rn(v.y * inv);
  r.z = (char)__float2int_rn(v.z * inv);
  r.w = (char)__float2int_rn(v.w * inv);
  o[i] = r;
}

__global__ void dequant_w8(const int4* __restrict__ q, char4* __restrict__ o, int n4,
                           const int* __restrict__ z) {
  int i = blockIdx.x * 256 + threadIdx.x;
  if (i >= n4) return;
  const int zv = z[0];
  int4 v = q[i];
  char4 r;
  r.x = (char)(v.x - zv); r.y = (char)(v.y - zv);
  r.z = (char)(v.z - zv); r.w = (char)(v.w - zv);
  o[i] = r;
}

__global__ void dequant4(const int4* __restrict__ q, ushort4* __restrict__ o, int n4,
                         const float* __restrict__ s, const int* __restrict__ z) {
  int i = blockIdx.x * 256 + threadIdx.x;
  if (i >= n4) return;
  const float sv = s[0];
  const int zv = z[0];
  int4 v = q[i];
  ushort4 r;
  r.x = f2bf(sv * (float)(v.x - zv));
  r.y = f2bf(sv * (float)(v.y - zv));
  r.z = f2bf(sv * (float)(v.z - zv));
  r.w = f2bf(sv * (float)(v.w - zv));
  o[i] = r;
}

// ---------------- i8 BT GEMM (QKV): 256x256 tile, BK=128, 8-wave, ----------
// 4-phase/K-tile pipelined schedule with counted vmcnt(8) (T2+T3+T4+T5).
// LDS = 2 slots x (32KB A + 32KB B) = 128KB. Rows are 128B with chunk
// swizzle c^(row&7) (conflict-free ds_read_b128, same as the R7-verified
// 128^2 kernel). Stage/drain liveness (hand-verified, see session notes):
//   iter T (slot CUR): ph0: stage A-Q0(T+2,CUR)          ; ds b1(CUR) ; mfma(a0,b0)
//                      ph1:                               ; ds a1(CUR) ; mfma(a0,b1)
//                      ph2: stage A-Q1,B-S0(T+2,CUR)     ;            ; mfma(a1,b0); vmcnt(8)
//                      ph3: stage B-S1(T+2,CUR)          ; ds a0,b0(NXT); mfma(a1,b1); vmcnt(8)
// ph2's vmcnt(8) drains prev-slot A-Q0/A-Q1/B-S0 (read in ph3); ph3's
// drains prev-slot B-S1 (read next ph0). Never drains to 0 in-loop.

#define STAGE_A(Q, C, KK, SL) do {                                           \
    const int row_ = (C)*128 + (Q)*64 + (tid>>3);                            \
    const int ch_ = (tid&7) ^ (row_&7);                                      \
    async16(A + (size_t)(Mb + row_)*2048 + (KK) + ch_*16,                    \
            sA + (SL)*32768 + (C)*16384 + (Q)*8192 + tid*16);                \
  } while(0)

#define STAGE_B(S, C, KK, SL) do {                                           \
    const int t8_ = tid & 255, hi_ = tid >> 8;                               \
    const int row_ = (C)*128 + hi_*64 + (S)*32 + (t8_>>3);                   \
    const int ch_ = (tid&7) ^ (row_&7);                                      \
    async16(B + (size_t)(Nb + row_)*2048 + (KK) + ch_*16,                    \
            sB + (SL)*32768 + (C)*16384 + hi_*8192 + (S)*4096 + t8_*16);     \
  } while(0)

#define LDA(DST, MQ, SL)                                                     \
  _Pragma("unroll")                                                          \
  for (int mp_ = 0; mp_ < 4; ++mp_)                                          \
    _Pragma("unroll")                                                        \
    for (int ks_ = 0; ks_ < 2; ++ks_) {                                      \
      const int r_ = wm*128 + (MQ)*64 + mp_*16 + l16;                        \
      DST[mp_][ks_] = *(const i32x4*)(sA + (SL)*32768 + r_*128 +             \
                                      ((((ks_<<2)+quad) ^ (r_&7)) << 4));    \
    }

#define LDB(DST, NQ, SL)                                                     \
  _Pragma("unroll")                                                          \
  for (int np_ = 0; np_ < 2; ++np_)                                          \
    _Pragma("unroll")                                                        \
    for (int ks_ = 0; ks_ < 2; ++ks_) {                                      \
      const int r_ = wn*64 + (NQ)*32 + np_*16 + l16;                         \
      DST[np_][ks_] = *(const i32x4*)(sB + (SL)*32768 + r_*128 +             \
                                      ((((ks_<<2)+quad) ^ (r_&7)) << 4));    \
    }

#define MFMA_QUAD(AF, BF, MQ, NQ)                                            \
  _Pragma("unroll")                                                          \
  for (int ks_ = 0; ks_ < 2; ++ks_)                                          \
    _Pragma("unroll")                                                        \
    for (int mp_ = 0; mp_ < 4; ++mp_)                                        \
      _Pragma("unroll")                                                      \
      for (int np_ = 0; np_ < 2; ++np_)                                      \
        acc[(MQ)*4+mp_][(NQ)*2+np_] = __builtin_amdgcn_mfma_i32_16x16x64_i8( \
            AF[mp_][ks_], BF[np_][ks_], acc[(MQ)*4+mp_][(NQ)*2+np_], 0, 0, 0);

#define BARRIER __builtin_amdgcn_s_barrier()
#define WAIT_LGKM0 do { asm volatile("s_waitcnt lgkmcnt(0)" ::: "memory");   \
                        __builtin_amdgcn_sched_barrier(0); } while(0)
#define WAIT_VM8 asm volatile("s_waitcnt vmcnt(8)" ::: "memory")

#define ITER(CUR, NXT, KK2) do {                                             \
    /* phase 0 */                                                            \
    STAGE_A(0,0,KK2,CUR); STAGE_A(0,1,KK2,CUR);                              \
    LDB(b1, 1, CUR);                                                         \
    BARRIER; WAIT_LGKM0;                                                     \
    __builtin_amdgcn_s_setprio(1);                                           \
    MFMA_QUAD(a0, b0, 0, 0);                                                 \
    __builtin_amdgcn_s_setprio(0);                                           \
    BARRIER;                                                                 \
    /* phase 1 */                                                            \
    LDA(a1, 1, CUR);                                                         \
    BARRIER; WAIT_LGKM0;                                                     \
    __builtin_amdgcn_s_setprio(1);                                           \
    MFMA_QUAD(a0, b1, 0, 1);                                                 \
    __builtin_amdgcn_s_setprio(0);                                           \
    BARRIER;                                                                 \
    /* phase 2 */                                                            \
    STAGE_A(1,0,KK2,CUR); STAGE_A(1,1,KK2,CUR);                              \
    STAGE_B(0,0,KK2,CUR); STAGE_B(0,1,KK2,CUR);                              \
    BARRIER; WAIT_LGKM0;                                                     \
    __builtin_amdgcn_s_setprio(1);                                           \
    MFMA_QUAD(a1, b0, 1, 0);                                                 \
    __builtin_amdgcn_s_setprio(0);                                           \
    WAIT_VM8;                                                                \
    BARRIER;                                                                 \
    /* phase 3 */                                                            \
    STAGE_B(1,0,KK2,CUR); STAGE_B(1,1,KK2,CUR);                              \
    LDA(a0, 0, NXT); LDB(b0, 0, NXT);                                        \
    BARRIER; WAIT_LGKM0;                                                     \
    __builtin_amdgcn_s_setprio(1);                                           \
    MFMA_QUAD(a1, b1, 1, 1);                                                 \
    __builtin_amdgcn_s_setprio(0);                                           \
    WAIT_VM8;                                                                \
    BARRIER;                                                                 \
  } while(0)

__global__ __launch_bounds__(512, 2) void gemm_i8_qkv(
    const char* __restrict__ A, const char* __restrict__ B, int K,
    const float* __restrict__ sw, const unsigned* __restrict__ amax,
    const int* __restrict__ bq, const float* __restrict__ bs, const int* __restrict__ bz,
    u16* __restrict__ qb, u16* __restrict__ kb, u16* __restrict__ vT) {
  __shared__ uint8_t sA[65536];
  __shared__ uint8_t sB[65536];
  const int tid = threadIdx.x;
  const int wave = tid >> 6, lane = tid & 63;
  const int quad = lane >> 4, l16 = lane & 15;
  const int wm = wave >> 2, wn = wave & 3;

  // bijective XCD swizzle: nwg = 16*24 = 384 = 8*48
  const int bid = blockIdx.y * 24 + blockIdx.x;
  const int swz = (bid & 7) * 48 + (bid >> 3);
  const int Nb = (swz % 24) << 8;
  const int Mb = (swz / 24) << 8;

  i32x4 acc[8][4] = {};
  i32x4 a0[4][2], a1[4][2];
  i32x4 b0[2][2], b1[2][2];

  // prologue: stage tiles 0 and 1 (issue order A-Q0,A-Q1,B-S0,B-S1 per tile)
  STAGE_A(0,0,0,0); STAGE_A(0,1,0,0); STAGE_A(1,0,0,0); STAGE_A(1,1,0,0);
  STAGE_B(0,0,0,0); STAGE_B(0,1,0,0); STAGE_B(1,0,0,0); STAGE_B(1,1,0,0);
  STAGE_A(0,0,128,1); STAGE_A(0,1,128,1); STAGE_A(1,0,128,1); STAGE_A(1,1,128,1);
  STAGE_B(0,0,128,1); STAGE_B(0,1,128,1); STAGE_B(1,0,128,1); STAGE_B(1,1,128,1);
  WAIT_VM8;   // drains all 8 tile-0 loads, leaves tile-1's 8 in flight
  BARRIER;
  LDA(a0, 0, 0); LDB(b0, 0, 0);
  WAIT_LGKM0; // drain prologue ds_reads before iter0-ph0 restages A-Q0(slot0)
  BARRIER;

#pragma unroll 1
  for (int T2 = 0; T2 < 8; ++T2) {
    const int ta = 2 * T2 + 2, tb = 2 * T2 + 3;
    const int kka = (ta < 16 ? ta : 15) << 7;   // clamp keeps vmcnt counts uniform
    const int kkb = (tb < 16 ? tb : 15) << 7;
    ITER(0, 1, kka);
    ITER(1, 0, kkb);
  }
  asm volatile("s_waitcnt vmcnt(0)" ::: "memory");  // drain stray prefetches

  const float sv = sw[0] * (__uint_as_float(amax[0]) / 127.0f);
  const float sbv = bs[0];
  const int zbv = bz[0];
#pragma unroll
  for (int nn = 0; nn < 4; ++nn) {
    const int o = Nb + wn * 64 + nn * 16 + l16;
    const float bias = sbv * (float)(bq[o] - zbv);
    const int which = o >> 11;
    const int cc = o & 2047;
    const int h = cc >> 7, d = cc & 127;
#pragma unroll
    for (int mm = 0; mm < 8; ++mm) {
      const int m0 = Mb + wm * 128 + mm * 16 + quad * 4;
      const int bi = m0 >> 10, t0 = m0 & 1023;
      const size_t bhx = (size_t)bi * 16 + h;
      if (which == 2) {
        ushort4 pv;
        pv.x = f2bf((float)acc[mm][nn][0] * sv + bias);
        pv.y = f2bf((float)acc[mm][nn][1] * sv + bias);
        pv.z = f2bf((float)acc[mm][nn][2] * sv + bias);
        pv.w = f2bf((float)acc[mm][nn][3] * sv + bias);
        *(ushort4*)(vT + (bhx * 128 + d) * 1024 + t0) = pv;
      } else {
        u16* dst = (which == 0 ? qb : kb) + (bhx * 1024 + t0) * 128 + d;
#pragma unroll
        for (int r = 0; r < 4; ++r) dst[r * 128] = f2bf((float)acc[mm][nn][r] * sv + bias);
      }
    }
  }
}

// ---------------- bf16 BT GEMM (proj, verified) ----------------
__global__ __launch_bounds__(256, 2) void gemm_bt_out(
    const u16* __restrict__ A, const u16* __restrict__ B, int K, int N,
    const int* __restrict__ bq, const float* __restrict__ bs, const int* __restrict__ bz,
    float* __restrict__ out) {
  __shared__ uint8_t sA[16384];
  __shared__ uint8_t sB[16384];
  const int tid = threadIdx.x;
  const int wave = tid >> 6, lane = tid & 63;
  const int quad = lane >> 4, l16 = lane & 15;
  const int wm = wave >> 1, wn = wave & 1;
  const int Mb = blockIdx.y << 7, Nb = blockIdx.x << 7;

  const u16* ag[4];
  const u16* bg[4];
  int lo[4];
#pragma unroll
  for (int i = 0; i < 4; ++i) {
    int row = wave * 32 + i * 8 + (lane >> 3);
    int c = (lane & 7) ^ (row & 7);
    ag[i] = A + (size_t)(Mb + row) * K + c * 8;
    bg[i] = B + (size_t)(Nb + row) * K + c * 8;
    lo[i] = wave * 4096 + i * 1024 + lane * 16;
  }

  f32x4 acc[4][4] = {};

  for (int kk = 0; kk < K; kk += 64) {
    __syncthreads();
#pragma unroll
    for (int i = 0; i < 4; ++i) {
      async16(ag[i] + kk, sA + lo[i]);
      async16(bg[i] + kk, sB + lo[i]);
    }
    __syncthreads();
#pragma unroll
    for (int ks = 0; ks < 2; ++ks) {
      bf16x8 af[4], bfr[4];
#pragma unroll
      for (int t = 0; t < 4; ++t) {
        int m = wm * 64 + t * 16 + l16;
        af[t] = *(const bf16x8*)(sA + m * 128 + ((((ks << 2) + quad) ^ (m & 7)) << 4));
        int n = wn * 64 + t * 16 + l16;
        bfr[t] = *(const bf16x8*)(sB + n * 128 + ((((ks << 2) + quad) ^ (n & 7)) << 4));
      }
#pragma unroll
      for (int mt = 0; mt < 4; ++mt)
#pragma unroll
        for (int nt = 0; nt < 4; ++nt)
          acc[mt][nt] = __builtin_amdgcn_mfma_f32_16x16x32_bf16(af[mt], bfr[nt], acc[mt][nt], 0, 0, 0);
    }
  }

  const float sbv = bs[0];
  const int zbv = bz[0];
#pragma unroll
  for (int nt = 0; nt < 4; ++nt) {
    const int o = Nb + wn * 64 + nt * 16 + l16;
    const float bias = sbv * (float)(bq[o] - zbv);
#pragma unroll
    for (int mt = 0; mt < 4; ++mt) {
      const int m0 = Mb + wm * 64 + mt * 16 + quad * 4;
#pragma unroll
      for (int r = 0; r < 4; ++r)
        out[(size_t)(m0 + r) * N + o] = acc[mt][nt][r] + bias;
    }
  }
}

// ---------------- flash attention: q128 (Q regs), kv64, 48KB LDS, max-free softmax ----
__global__ __launch_bounds__(256, 2) void attn_fwd(
    const u16* __restrict__ qg, const u16* __restrict__ kg,
    const u16* __restrict__ vg, u16* __restrict__ yb) {
  __shared__ uint8_t smem[49152];
  uint8_t* sK = smem;           // K: 64 x 256B, chunk swz ^(row&15); Q staged over sK+sV
  uint8_t* sV = smem + 16384;   // V^T: 128 d-rows x 64 t (128B rows, swz ^(d&7))
  uint8_t* sP = smem + 32768;   // P: 128 q-rows x 64 k (128B rows, swz ^(row&7))
  const int tid = threadIdx.x;
  const int wave = tid >> 6, lane = tid & 63;
  const int quad = lane >> 4, l16 = lane & 15;
  const int bh = blockIdx.x;
  const int y = blockIdx.y;
  const int qi = (y < 4) ? (7 - y) : (y - 4);
  const int qbase = qi << 7;
  const size_t base = (size_t)bh << 17;
  const u16* Q = qg + base;
  const u16* Kp = kg + base;
  const u16* Vp = vg + base;

#pragma unroll
  for (int i = 0; i < 8; ++i) {
    int off = wave * 8192 + i * 1024;
    int row = (off >> 8) + quad;
    int c = l16 ^ (row & 15);
    async16(Q + (size_t)(qbase + row) * 128 + c * 8, smem + off + lane * 16);
  }
  __syncthreads();
  bf16x8 qf[2][4];
#pragma unroll
  for (int mi = 0; mi < 2; ++mi)
#pragma unroll
    for (int ks = 0; ks < 4; ++ks) {
      int m = wave * 32 + mi * 16 + l16;
      qf[mi][ks] = *(const bf16x8*)(smem + m * 256 + ((((ks << 2) + quad) ^ (m & 15)) << 4));
    }

  f32x4 accO[2][8] = {};
  float lacc[2][4] = {};

  const float scale = 0.088388347648318447f;  // 1/sqrt(128)
  const int jmax = 2 * qi + 1;

  for (int j = 0; j <= jmax; ++j) {
    const int tb = j << 6;
    __syncthreads();
#pragma unroll
    for (int i = 0; i < 4; ++i) {
      int off = wave * 4096 + i * 1024;
      int rowk = (off >> 8) + quad;
      int ck = l16 ^ (rowk & 15);
      async16(Kp + (size_t)(tb + rowk) * 128 + ck * 8, sK + off + lane * 16);
      int rowd = (off >> 7) + (lane >> 3);
      int cv = (lane & 7) ^ (rowd & 7);
      async16(Vp + (size_t)rowd * 1024 + tb + cv * 8, sV + off + lane * 16);
    }
    __syncthreads();

    f32x4 sc[2][4] = {};
#pragma unroll
    for (int ks = 0; ks < 4; ++ks) {
      bf16x8 kf[4];
#pragma unroll
      for (int ni = 0; ni < 4; ++ni) {
        int n = ni * 16 + l16;
        kf[ni] = *(const bf16x8*)(sK + n * 256 + ((((ks << 2) + quad) ^ (n & 15)) << 4));
      }
#pragma unroll
      for (int mi = 0; mi < 2; ++mi)
#pragma unroll
        for (int ni = 0; ni < 4; ++ni)
          sc[mi][ni] = __builtin_amdgcn_mfma_f32_16x16x32_bf16(qf[mi][ks], kf[ni], sc[mi][ni], 0, 0, 0);
    }

    const bool needmask = (tb + 63) > qbase;
#pragma unroll
    for (int mi = 0; mi < 2; ++mi) {
      const int row0 = qbase + wave * 32 + mi * 16 + quad * 4;
#pragma unroll
      for (int ni = 0; ni < 4; ++ni) {
        const int col = tb + ni * 16 + l16;
#pragma unroll
        for (int r = 0; r < 4; ++r) {
          float s = sc[mi][ni][r] * scale;
          if (needmask && col > row0 + r) s = -INFINITY;
          float p = __expf(s);
          sc[mi][ni][r] = p;
          lacc[mi][r] += p;
        }
      }
    }

#pragma unroll
    for (int mi = 0; mi < 2; ++mi)
#pragma unroll
      for (int ni = 0; ni < 4; ++ni)
#pragma unroll
        for (int r = 0; r < 4; ++r) {
          int qr = wave * 32 + mi * 16 + quad * 4 + r;
          int kc = ni * 16 + l16;
          *(u16*)(sP + qr * 128 + (((kc >> 3) ^ (qr & 7)) << 4) + (kc & 7) * 2) =
              f2bf(sc[mi][ni][r]);
        }

#pragma unroll
    for (int ks = 0; ks < 2; ++ks) {
      bf16x8 pf[2], vf[8];
#pragma unroll
      for (int mi = 0; mi < 2; ++mi) {
        int m = wave * 32 + mi * 16 + l16;
        pf[mi] = *(const bf16x8*)(sP + m * 128 + ((((ks << 2) + quad) ^ (m & 7)) << 4));
      }
#pragma unroll
      for (int ni = 0; ni < 8; ++ni) {
        int n = ni * 16 + l16;
        vf[ni] = *(const bf16x8*)(sV + n * 128 + ((((ks << 2) + quad) ^ (n & 7)) << 4));
      }
#pragma unroll
      for (int mi = 0; mi < 2; ++mi)
#pragma unroll
        for (int ni = 0; ni < 8; ++ni)
          accO[mi][ni] = __builtin_amdgcn_mfma_f32_16x16x32_bf16(pf[mi], vf[ni], accO[mi][ni], 0, 0, 0);
    }
  }

  const int b = bh >> 4, h = bh & 15;
#pragma unroll
  for (int mi = 0; mi < 2; ++mi) {
    float inv[4];
#pragma unroll
    for (int r = 0; r < 4; ++r) {
      float l = lacc[mi][r];
#pragma unroll
      for (int x = 1; x < 16; x <<= 1) l += __shfl_xor(l, x);
      inv[r] = 1.0f / l;
    }
#pragma unroll
    for (int ni = 0; ni < 8; ++ni)
#pragma unroll
      for (int r = 0; r < 4; ++r) {
        int row = qbase + wave * 32 + mi * 16 + quad * 4 + r;
        int col = (h << 7) + ni * 16 + l16;
        yb[((size_t)(b * 1024 + row) << 11) + col] = f2bf(accO[mi][ni][r] * inv[r]);
      }
  }
}

// ---------------- launch ----------------
extern "C" void kernel_launch(void* const* d_in, const int* in_sizes, int n_in,
                              void* d_out, int out_size, void* d_ws, size_t ws_size,
                              hipStream_t stream) {
  const float* x = (const float*)d_in[0];
  const int* waq = (const int*)d_in[1];
  const float* s_wa = (const float*)d_in[2];
  const int* z_wa = (const int*)d_in[3];
  const int* baq = (const int*)d_in[4];
  const float* s_ba = (const float*)d_in[5];
  const int* z_ba = (const int*)d_in[6];
  const int* wpq = (const int*)d_in[7];
  const float* s_wp = (const float*)d_in[8];
  const int* z_wp = (const int*)d_in[9];
  const int* bpq = (const int*)d_in[10];
  const float* s_bp = (const float*)d_in[11];
  const int* z_bp = (const int*)d_in[12];

  // workspace: xq[0,8) wa8[8,20) wp_bf[20,28) qb[28,44) kb[44,60) vT[60,76) yb[76,92) amax[92] MiB
  char* ws = (char*)d_ws;
  char* xq    = ws + 0;
  char* wa8   = ws + 8388608;
  u16* wp_bf  = (u16*)(ws + 20971520);
  u16* qb     = (u16*)(ws + 29360128);
  u16* kb     = (u16*)(ws + 46137344);
  u16* vT     = (u16*)(ws + 62914560);
  u16* yb     = (u16*)(ws + 79691776);
  unsigned* amax = (unsigned*)(ws + 96468992);

  hipMemsetAsync(amax, 0, 4, stream);
  absmax_x<<<1024, 256, 0, stream>>>((const float4*)x, amax, 2097152);
  quant_x<<<8192, 256, 0, stream>>>((const float4*)x, (char4*)xq, amax, 2097152);
  dequant_w8<<<12288, 256, 0, stream>>>((const int4*)waq, (char4*)wa8, 3145728, z_wa);
  dequant4<<<4096, 256, 0, stream>>>((const int4*)wpq, (ushort4*)wp_bf, 1048576, s_wp, z_wp);

  gemm_i8_qkv<<<dim3(24, 16), 512, 0, stream>>>(xq, wa8, 2048, s_wa, amax,
                                                baq, s_ba, z_ba, qb, kb, vT);

  attn_fwd<<<dim3(64, 8), 256, 0, stream>>>(qb, kb, vT, yb);

  gemm_bt_out<<<dim3(16, 32), 256, 0, stream>>>(yb, wp_bf, 2048, 2048,
                                                bpq, s_bp, z_bp, (float*)d_out);
}

// Round 3
// 358.074 us; speedup vs baseline: 1.0361x; 1.0361x over previous
//
#include <hip/hip_runtime.h>
#include <stdint.h>
#include <math.h>

typedef unsigned short u16;
typedef __attribute__((ext_vector_type(4))) float f32x4;
typedef __attribute__((ext_vector_type(4))) int i32x4;
typedef __attribute__((ext_vector_type(8))) short bf16x8;

__device__ __forceinline__ u16 f2bf(float f) {
  uint32_t u = __float_as_uint(f);
  u += 0x7FFFu + ((u >> 16) & 1u);
  return (u16)(u >> 16);
}

__device__ __forceinline__ void async16(const void* g, void* l) {
  __builtin_amdgcn_global_load_lds(
      (const __attribute__((address_space(1))) void*)g,
      (__attribute__((address_space(3))) void*)l, 16, 0, 0);
}

// ---------------- prep ----------------
__global__ void absmax_x(const float4* __restrict__ x, unsigned* __restrict__ amax, int n4) {
  int i = blockIdx.x * 256 + threadIdx.x;
  float m = 0.f;
  for (; i < n4; i += gridDim.x * 256) {
    float4 v = x[i];
    m = fmaxf(m, fmaxf(fmaxf(fabsf(v.x), fabsf(v.y)), fmaxf(fabsf(v.z), fabsf(v.w))));
  }
#pragma unroll
  for (int s = 1; s < 64; s <<= 1) m = fmaxf(m, __shfl_xor(m, s));
  if ((threadIdx.x & 63) == 0) atomicMax(amax, __float_as_uint(m));
}

__global__ void quant_x(const float4* __restrict__ x, char4* __restrict__ o,
                        const unsigned* __restrict__ amax, int n4) {
  int i = blockIdx.x * 256 + threadIdx.x;
  if (i >= n4) return;
  const float inv = 127.0f / __uint_as_float(amax[0]);
  float4 v = x[i];
  char4 r;
  r.x = (char)__float2int_rn(v.x * inv);
  r.y = (char)__float2int_rn(v.y * inv);
  r.z = (char)__float2int_rn(v.z * inv);
  r.w = (char)__float2int_rn(v.w * inv);
  o[i] = r;
}

__global__ void dequant_w8(const int4* __restrict__ q, char4* __restrict__ o, int n4,
                           const int* __restrict__ z) {
  int i = blockIdx.x * 256 + threadIdx.x;
  if (i >= n4) return;
  const int zv = z[0];
  int4 v = q[i];
  char4 r;
  r.x = (char)(v.x - zv); r.y = (char)(v.y - zv);
  r.z = (char)(v.z - zv); r.w = (char)(v.w - zv);
  o[i] = r;
}

__global__ void dequant4(const int4* __restrict__ q, ushort4* __restrict__ o, int n4,
                         const float* __restrict__ s, const int* __restrict__ z) {
  int i = blockIdx.x * 256 + threadIdx.x;
  if (i >= n4) return;
  const float sv = s[0];
  const int zv = z[0];
  int4 v = q[i];
  ushort4 r;
  r.x = f2bf(sv * (float)(v.x - zv));
  r.y = f2bf(sv * (float)(v.y - zv));
  r.z = f2bf(sv * (float)(v.z - zv));
  r.w = f2bf(sv * (float)(v.w - zv));
  o[i] = r;
}

// ---------------- i8 BT GEMM (QKV): 128(M)x256(N) tile, BK=128, 8 waves ----
// Ring-3 LDS (tiles t, t+1, t+2 live), depth-2 counted prefetch:
//   per iter: issue 6 stage loads (tile t+2, slot (t+2)%3)
//             16 ds_read_b128 (tile t, slot t%3); lgkmcnt(0)
//             32 MFMA; vmcnt(6) [drains tile t+1's 6, leaves t+2's 6]
//             s_barrier
// Never drains vmcnt to 0 in-loop; prefetch distance = 2 iters (~2600 cyc).
// Grid 24x32 = 768 blocks = 3 exact rounds at 1 block/CU (no tail);
// natural dispatch (bid%8 = x%8) gives the good N-partition per XCD
// (full A 8MB + 1.5MB B-slice = 9.5MB/XCD, as the round-0 baseline).
// Swizzle/read conventions identical to the HW-verified round-0/R2 code.

#define QSTAGE_A(KK, SL) do {                                                \
    _Pragma("unroll")                                                        \
    for (int c_ = 0; c_ < 2; ++c_) {                                         \
      const int row_ = c_*64 + (tid>>3);                                     \
      const int ch_ = (tid&7) ^ (row_&7);                                    \
      async16(A + (size_t)(Mb + row_)*2048 + (KK) + ch_*16,                  \
              sA + (SL)*16384 + c_*8192 + tid*16);                           \
    }                                                                        \
  } while(0)

#define QSTAGE_B(KK, SL) do {                                                \
    _Pragma("unroll")                                                        \
    for (int c_ = 0; c_ < 4; ++c_) {                                         \
      const int row_ = c_*64 + (tid>>3);                                     \
      const int ch_ = (tid&7) ^ (row_&7);                                    \
      async16(Bm + (size_t)(Nb + row_)*2048 + (KK) + ch_*16,                 \
              sB + (SL)*32768 + c_*8192 + tid*16);                           \
    }                                                                        \
  } while(0)

__global__ __launch_bounds__(512, 2) void gemm_i8_qkv(
    const char* __restrict__ A, const char* __restrict__ Bm, int K,
    const float* __restrict__ sw, const unsigned* __restrict__ amax,
    const int* __restrict__ bq, const float* __restrict__ bs, const int* __restrict__ bz,
    u16* __restrict__ qb, u16* __restrict__ kb, u16* __restrict__ vT) {
  __shared__ uint8_t sA[49152];   // 3 slots x 128 rows x 128B
  __shared__ uint8_t sB[98304];   // 3 slots x 256 rows x 128B
  const int tid = threadIdx.x;
  const int wave = tid >> 6, lane = tid & 63;
  const int quad = lane >> 4, l16 = lane & 15;
  const int wm = wave >> 2, wn = wave & 3;  // 2M x 4N waves, 64x64 each
  const int Mb = blockIdx.y << 7, Nb = blockIdx.x << 8;

  i32x4 acc[4][4] = {};

  // prologue: tiles 0,1 -> slots 0,1 (6 loads each)
  QSTAGE_A(0, 0); QSTAGE_B(0, 0);
  QSTAGE_A(128, 1); QSTAGE_B(128, 1);
  asm volatile("s_waitcnt vmcnt(6)" ::: "memory");  // tile-0 complete
  __builtin_amdgcn_s_barrier();

  int slr = 0, slw = 2;
#pragma unroll 1
  for (int t = 0; t < 16; ++t) {
    const int kst = (t + 2 < 16 ? t + 2 : 15) << 7;  // clamp keeps counts uniform
    QSTAGE_A(kst, slw); QSTAGE_B(kst, slw);

    i32x4 af[4][2], bf[4][2];
#pragma unroll
    for (int mt = 0; mt < 4; ++mt)
#pragma unroll
      for (int ks = 0; ks < 2; ++ks) {
        const int r = wm * 64 + mt * 16 + l16;
        af[mt][ks] = *(const i32x4*)(sA + slr * 16384 + r * 128 +
                                     ((((ks << 2) + quad) ^ (r & 7)) << 4));
      }
#pragma unroll
    for (int nt = 0; nt < 4; ++nt)
#pragma unroll
      for (int ks = 0; ks < 2; ++ks) {
        const int r = wn * 64 + nt * 16 + l16;
        bf[nt][ks] = *(const i32x4*)(sB + slr * 32768 + r * 128 +
                                     ((((ks << 2) + quad) ^ (r & 7)) << 4));
      }
    asm volatile("s_waitcnt lgkmcnt(0)" ::: "memory");
    __builtin_amdgcn_sched_barrier(0);
#pragma unroll
    for (int ks = 0; ks < 2; ++ks)
#pragma unroll
      for (int mt = 0; mt < 4; ++mt)
#pragma unroll
        for (int nt = 0; nt < 4; ++nt)
          acc[mt][nt] = __builtin_amdgcn_mfma_i32_16x16x64_i8(af[mt][ks], bf[nt][ks],
                                                              acc[mt][nt], 0, 0, 0);
    asm volatile("s_waitcnt vmcnt(6)" ::: "memory");  // tile t+1 complete
    __builtin_amdgcn_s_barrier();
    slr = (slr == 2) ? 0 : slr + 1;
    slw = (slw == 2) ? 0 : slw + 1;
  }
  asm volatile("s_waitcnt vmcnt(0)" ::: "memory");  // drain clamped prefetches

  const float sv = sw[0] * (__uint_as_float(amax[0]) / 127.0f);
  const float sbv = bs[0];
  const int zbv = bz[0];
#pragma unroll
  for (int nt = 0; nt < 4; ++nt) {
    const int o = Nb + wn * 64 + nt * 16 + l16;
    const float bias = sbv * (float)(bq[o] - zbv);
    const int which = o >> 11;
    const int cc = o & 2047;
    const int h = cc >> 7, d = cc & 127;
#pragma unroll
    for (int mt = 0; mt < 4; ++mt) {
      const int m0 = Mb + wm * 64 + mt * 16 + quad * 4;
      const int bi = m0 >> 10, t0 = m0 & 1023;
      const size_t bhx = (size_t)bi * 16 + h;
      if (which == 2) {
        ushort4 pv;
        pv.x = f2bf((float)acc[mt][nt][0] * sv + bias);
        pv.y = f2bf((float)acc[mt][nt][1] * sv + bias);
        pv.z = f2bf((float)acc[mt][nt][2] * sv + bias);
        pv.w = f2bf((float)acc[mt][nt][3] * sv + bias);
        *(ushort4*)(vT + (bhx * 128 + d) * 1024 + t0) = pv;
      } else {
        u16* dst = (which == 0 ? qb : kb) + (bhx * 1024 + t0) * 128 + d;
#pragma unroll
        for (int r = 0; r < 4; ++r) dst[r * 128] = f2bf((float)acc[mt][nt][r] * sv + bias);
      }
    }
  }
}

// ---------------- bf16 BT GEMM (proj, verified) ----------------
__global__ __launch_bounds__(256, 2) void gemm_bt_out(
    const u16* __restrict__ A, const u16* __restrict__ B, int K, int N,
    const int* __restrict__ bq, const float* __restrict__ bs, const int* __restrict__ bz,
    float* __restrict__ out) {
  __shared__ uint8_t sA[16384];
  __shared__ uint8_t sB[16384];
  const int tid = threadIdx.x;
  const int wave = tid >> 6, lane = tid & 63;
  const int quad = lane >> 4, l16 = lane & 15;
  const int wm = wave >> 1, wn = wave & 1;
  const int Mb = blockIdx.y << 7, Nb = blockIdx.x << 7;

  const u16* ag[4];
  const u16* bg[4];
  int lo[4];
#pragma unroll
  for (int i = 0; i < 4; ++i) {
    int row = wave * 32 + i * 8 + (lane >> 3);
    int c = (lane & 7) ^ (row & 7);
    ag[i] = A + (size_t)(Mb + row) * K + c * 8;
    bg[i] = B + (size_t)(Nb + row) * K + c * 8;
    lo[i] = wave * 4096 + i * 1024 + lane * 16;
  }

  f32x4 acc[4][4] = {};

  for (int kk = 0; kk < K; kk += 64) {
    __syncthreads();
#pragma unroll
    for (int i = 0; i < 4; ++i) {
      async16(ag[i] + kk, sA + lo[i]);
      async16(bg[i] + kk, sB + lo[i]);
    }
    __syncthreads();
#pragma unroll
    for (int ks = 0; ks < 2; ++ks) {
      bf16x8 af[4], bfr[4];
#pragma unroll
      for (int t = 0; t < 4; ++t) {
        int m = wm * 64 + t * 16 + l16;
        af[t] = *(const bf16x8*)(sA + m * 128 + ((((ks << 2) + quad) ^ (m & 7)) << 4));
        int n = wn * 64 + t * 16 + l16;
        bfr[t] = *(const bf16x8*)(sB + n * 128 + ((((ks << 2) + quad) ^ (n & 7)) << 4));
      }
#pragma unroll
      for (int mt = 0; mt < 4; ++mt)
#pragma unroll
        for (int nt = 0; nt < 4; ++nt)
          acc[mt][nt] = __builtin_amdgcn_mfma_f32_16x16x32_bf16(af[mt], bfr[nt], acc[mt][nt], 0, 0, 0);
    }
  }

  const float sbv = bs[0];
  const int zbv = bz[0];
#pragma unroll
  for (int nt = 0; nt < 4; ++nt) {
    const int o = Nb + wn * 64 + nt * 16 + l16;
    const float bias = sbv * (float)(bq[o] - zbv);
#pragma unroll
    for (int mt = 0; mt < 4; ++mt) {
      const int m0 = Mb + wm * 64 + mt * 16 + quad * 4;
#pragma unroll
      for (int r = 0; r < 4; ++r)
        out[(size_t)(m0 + r) * N + o] = acc[mt][nt][r] + bias;
    }
  }
}

// ---------------- flash attention: q128 (Q regs), kv64, 48KB LDS, max-free softmax ----
__global__ __launch_bounds__(256, 2) void attn_fwd(
    const u16* __restrict__ qg, const u16* __restrict__ kg,
    const u16* __restrict__ vg, u16* __restrict__ yb) {
  __shared__ uint8_t smem[49152];
  uint8_t* sK = smem;           // K: 64 x 256B, chunk swz ^(row&15); Q staged over sK+sV
  uint8_t* sV = smem + 16384;   // V^T: 128 d-rows x 64 t (128B rows, swz ^(d&7))
  uint8_t* sP = smem + 32768;   // P: 128 q-rows x 64 k (128B rows, swz ^(row&7))
  const int tid = threadIdx.x;
  const int wave = tid >> 6, lane = tid & 63;
  const int quad = lane >> 4, l16 = lane & 15;
  const int bh = blockIdx.x;
  const int y = blockIdx.y;
  const int qi = (y < 4) ? (7 - y) : (y - 4);
  const int qbase = qi << 7;
  const size_t base = (size_t)bh << 17;
  const u16* Q = qg + base;
  const u16* Kp = kg + base;
  const u16* Vp = vg + base;

#pragma unroll
  for (int i = 0; i < 8; ++i) {
    int off = wave * 8192 + i * 1024;
    int row = (off >> 8) + quad;
    int c = l16 ^ (row & 15);
    async16(Q + (size_t)(qbase + row) * 128 + c * 8, smem + off + lane * 16);
  }
  __syncthreads();
  bf16x8 qf[2][4];
#pragma unroll
  for (int mi = 0; mi < 2; ++mi)
#pragma unroll
    for (int ks = 0; ks < 4; ++ks) {
      int m = wave * 32 + mi * 16 + l16;
      qf[mi][ks] = *(const bf16x8*)(smem + m * 256 + ((((ks << 2) + quad) ^ (m & 15)) << 4));
    }

  f32x4 accO[2][8] = {};
  float lacc[2][4] = {};

  const float scale = 0.088388347648318447f;  // 1/sqrt(128)
  const int jmax = 2 * qi + 1;

  for (int j = 0; j <= jmax; ++j) {
    const int tb = j << 6;
    __syncthreads();
#pragma unroll
    for (int i = 0; i < 4; ++i) {
      int off = wave * 4096 + i * 1024;
      int rowk = (off >> 8) + quad;
      int ck = l16 ^ (rowk & 15);
      async16(Kp + (size_t)(tb + rowk) * 128 + ck * 8, sK + off + lane * 16);
      int rowd = (off >> 7) + (lane >> 3);
      int cv = (lane & 7) ^ (rowd & 7);
      async16(Vp + (size_t)rowd * 1024 + tb + cv * 8, sV + off + lane * 16);
    }
    __syncthreads();

    f32x4 sc[2][4] = {};
#pragma unroll
    for (int ks = 0; ks < 4; ++ks) {
      bf16x8 kf[4];
#pragma unroll
      for (int ni = 0; ni < 4; ++ni) {
        int n = ni * 16 + l16;
        kf[ni] = *(const bf16x8*)(sK + n * 256 + ((((ks << 2) + quad) ^ (n & 15)) << 4));
      }
#pragma unroll
      for (int mi = 0; mi < 2; ++mi)
#pragma unroll
        for (int ni = 0; ni < 4; ++ni)
          sc[mi][ni] = __builtin_amdgcn_mfma_f32_16x16x32_bf16(qf[mi][ks], kf[ni], sc[mi][ni], 0, 0, 0);
    }

    const bool needmask = (tb + 63) > qbase;
#pragma unroll
    for (int mi = 0; mi < 2; ++mi) {
      const int row0 = qbase + wave * 32 + mi * 16 + quad * 4;
#pragma unroll
      for (int ni = 0; ni < 4; ++ni) {
        const int col = tb + ni * 16 + l16;
#pragma unroll
        for (int r = 0; r < 4; ++r) {
          float s = sc[mi][ni][r] * scale;
          if (needmask && col > row0 + r) s = -INFINITY;
          float p = __expf(s);
          sc[mi][ni][r] = p;
          lacc[mi][r] += p;
        }
      }
    }

#pragma unroll
    for (int mi = 0; mi < 2; ++mi)
#pragma unroll
      for (int ni = 0; ni < 4; ++ni)
#pragma unroll
        for (int r = 0; r < 4; ++r) {
          int qr = wave * 32 + mi * 16 + quad * 4 + r;
          int kc = ni * 16 + l16;
          *(u16*)(sP + qr * 128 + (((kc >> 3) ^ (qr & 7)) << 4) + (kc & 7) * 2) =
              f2bf(sc[mi][ni][r]);
        }

#pragma unroll
    for (int ks = 0; ks < 2; ++ks) {
      bf16x8 pf[2], vf[8];
#pragma unroll
      for (int mi = 0; mi < 2; ++mi) {
        int m = wave * 32 + mi * 16 + l16;
        pf[mi] = *(const bf16x8*)(sP + m * 128 + ((((ks << 2) + quad) ^ (m & 7)) << 4));
      }
#pragma unroll
      for (int ni = 0; ni < 8; ++ni) {
        int n = ni * 16 + l16;
        vf[ni] = *(const bf16x8*)(sV + n * 128 + ((((ks << 2) + quad) ^ (n & 7)) << 4));
      }
#pragma unroll
      for (int mi = 0; mi < 2; ++mi)
#pragma unroll
        for (int ni = 0; ni < 8; ++ni)
          accO[mi][ni] = __builtin_amdgcn_mfma_f32_16x16x32_bf16(pf[mi], vf[ni], accO[mi][ni], 0, 0, 0);
    }
  }

  const int b = bh >> 4, h = bh & 15;
#pragma unroll
  for (int mi = 0; mi < 2; ++mi) {
    float inv[4];
#pragma unroll
    for (int r = 0; r < 4; ++r) {
      float l = lacc[mi][r];
#pragma unroll
      for (int x = 1; x < 16; x <<= 1) l += __shfl_xor(l, x);
      inv[r] = 1.0f / l;
    }
#pragma unroll
    for (int ni = 0; ni < 8; ++ni)
#pragma unroll
      for (int r = 0; r < 4; ++r) {
        int row = qbase + wave * 32 + mi * 16 + quad * 4 + r;
        int col = (h << 7) + ni * 16 + l16;
        yb[((size_t)(b * 1024 + row) << 11) + col] = f2bf(accO[mi][ni][r] * inv[r]);
      }
  }
}

// ---------------- launch ----------------
extern "C" void kernel_launch(void* const* d_in, const int* in_sizes, int n_in,
                              void* d_out, int out_size, void* d_ws, size_t ws_size,
                              hipStream_t stream) {
  const float* x = (const float*)d_in[0];
  const int* waq = (const int*)d_in[1];
  const float* s_wa = (const float*)d_in[2];
  const int* z_wa = (const int*)d_in[3];
  const int* baq = (const int*)d_in[4];
  const float* s_ba = (const float*)d_in[5];
  const int* z_ba = (const int*)d_in[6];
  const int* wpq = (const int*)d_in[7];
  const float* s_wp = (const float*)d_in[8];
  const int* z_wp = (const int*)d_in[9];
  const int* bpq = (const int*)d_in[10];
  const float* s_bp = (const float*)d_in[11];
  const int* z_bp = (const int*)d_in[12];

  // workspace: xq[0,8) wa8[8,20) wp_bf[20,28) qb[28,44) kb[44,60) vT[60,76) yb[76,92) amax[92] MiB
  char* ws = (char*)d_ws;
  char* xq    = ws + 0;
  char* wa8   = ws + 8388608;
  u16* wp_bf  = (u16*)(ws + 20971520);
  u16* qb     = (u16*)(ws + 29360128);
  u16* kb     = (u16*)(ws + 46137344);
  u16* vT     = (u16*)(ws + 62914560);
  u16* yb     = (u16*)(ws + 79691776);
  unsigned* amax = (unsigned*)(ws + 96468992);

  hipMemsetAsync(amax, 0, 4, stream);
  absmax_x<<<1024, 256, 0, stream>>>((const float4*)x, amax, 2097152);
  quant_x<<<8192, 256, 0, stream>>>((const float4*)x, (char4*)xq, amax, 2097152);
  dequant_w8<<<12288, 256, 0, stream>>>((const int4*)waq, (char4*)wa8, 3145728, z_wa);
  dequant4<<<4096, 256, 0, stream>>>((const int4*)wpq, (ushort4*)wp_bf, 1048576, s_wp, z_wp);

  gemm_i8_qkv<<<dim3(24, 32), 512, 0, stream>>>(xq, wa8, 2048, s_wa, amax,
                                                baq, s_ba, z_ba, qb, kb, vT);

  attn_fwd<<<dim3(64, 8), 256, 0, stream>>>(qb, kb, vT, yb);

  gemm_bt_out<<<dim3(16, 32), 256, 0, stream>>>(yb, wp_bf, 2048, 2048,
                                                bpq, s_bp, z_bp, (float*)d_out);
}

// Round 4
// 340.600 us; speedup vs baseline: 1.0893x; 1.0513x over previous
//
#include <hip/hip_runtime.h>
#include <stdint.h>
#include <math.h>

typedef unsigned short u16;
typedef __attribute__((ext_vector_type(4))) float f32x4;
typedef __attribute__((ext_vector_type(4))) int i32x4;
typedef __attribute__((ext_vector_type(8))) short bf16x8;

__device__ __forceinline__ u16 f2bf(float f) {
  uint32_t u = __float_as_uint(f);
  u += 0x7FFFu + ((u >> 16) & 1u);
  return (u16)(u >> 16);
}

__device__ __forceinline__ void async16(const void* g, void* l) {
  __builtin_amdgcn_global_load_lds(
      (const __attribute__((address_space(1))) void*)g,
      (__attribute__((address_space(3))) void*)l, 16, 0, 0);
}

// ---------------- prep ----------------
__global__ void absmax_x(const float4* __restrict__ x, unsigned* __restrict__ amax, int n4) {
  int i = blockIdx.x * 256 + threadIdx.x;
  float m = 0.f;
  for (; i < n4; i += gridDim.x * 256) {
    float4 v = x[i];
    m = fmaxf(m, fmaxf(fmaxf(fabsf(v.x), fabsf(v.y)), fmaxf(fabsf(v.z), fabsf(v.w))));
  }
#pragma unroll
  for (int s = 1; s < 64; s <<= 1) m = fmaxf(m, __shfl_xor(m, s));
  if ((threadIdx.x & 63) == 0) atomicMax(amax, __float_as_uint(m));
}

__global__ void quant_x(const float4* __restrict__ x, char4* __restrict__ o,
                        const unsigned* __restrict__ amax, int n4) {
  int i = blockIdx.x * 256 + threadIdx.x;
  if (i >= n4) return;
  const float inv = 127.0f / __uint_as_float(amax[0]);
  float4 v = x[i];
  char4 r;
  r.x = (char)__float2int_rn(v.x * inv);
  r.y = (char)__float2int_rn(v.y * inv);
  r.z = (char)__float2int_rn(v.z * inv);
  r.w = (char)__float2int_rn(v.w * inv);
  o[i] = r;
}

__global__ void dequant_w8(const int4* __restrict__ q, char4* __restrict__ o, int n4,
                           const int* __restrict__ z) {
  int i = blockIdx.x * 256 + threadIdx.x;
  if (i >= n4) return;
  const int zv = z[0];
  int4 v = q[i];
  char4 r;
  r.x = (char)(v.x - zv); r.y = (char)(v.y - zv);
  r.z = (char)(v.z - zv); r.w = (char)(v.w - zv);
  o[i] = r;
}

__global__ void dequant4(const int4* __restrict__ q, ushort4* __restrict__ o, int n4,
                         const float* __restrict__ s, const int* __restrict__ z) {
  int i = blockIdx.x * 256 + threadIdx.x;
  if (i >= n4) return;
  const float sv = s[0];
  const int zv = z[0];
  int4 v = q[i];
  ushort4 r;
  r.x = f2bf(sv * (float)(v.x - zv));
  r.y = f2bf(sv * (float)(v.y - zv));
  r.z = f2bf(sv * (float)(v.z - zv));
  r.w = f2bf(sv * (float)(v.w - zv));
  o[i] = r;
}

// ---------------- i8 BT GEMM (QKV, R7-verified round-0 version) ----------------
__global__ __launch_bounds__(256, 2) void gemm_i8_qkv(
    const char* __restrict__ A, const char* __restrict__ B, int K,
    const float* __restrict__ sw, const unsigned* __restrict__ amax,
    const int* __restrict__ bq, const float* __restrict__ bs, const int* __restrict__ bz,
    u16* __restrict__ qb, u16* __restrict__ kb, u16* __restrict__ vT) {
  __shared__ uint8_t sA[16384];
  __shared__ uint8_t sB[16384];
  const int tid = threadIdx.x;
  const int wave = tid >> 6, lane = tid & 63;
  const int quad = lane >> 4, l16 = lane & 15;
  const int wm = wave >> 1, wn = wave & 1;
  const int Mb = blockIdx.y << 7, Nb = blockIdx.x << 7;

  const char* ag[4];
  const char* bg[4];
  int lo[4];
#pragma unroll
  for (int i = 0; i < 4; ++i) {
    int row = wave * 32 + i * 8 + (lane >> 3);
    int c = (lane & 7) ^ (row & 7);
    ag[i] = A + (size_t)(Mb + row) * K + c * 16;
    bg[i] = B + (size_t)(Nb + row) * K + c * 16;
    lo[i] = wave * 4096 + i * 1024 + lane * 16;
  }

  i32x4 acc[4][4] = {};

  for (int kk = 0; kk < K; kk += 128) {
    __syncthreads();
#pragma unroll
    for (int i = 0; i < 4; ++i) {
      async16(ag[i] + kk, sA + lo[i]);
      async16(bg[i] + kk, sB + lo[i]);
    }
    __syncthreads();
#pragma unroll
    for (int ks = 0; ks < 2; ++ks) {
      i32x4 af[4], bfr[4];
#pragma unroll
      for (int t = 0; t < 4; ++t) {
        int m = wm * 64 + t * 16 + l16;
        af[t] = *(const i32x4*)(sA + m * 128 + ((((ks << 2) + quad) ^ (m & 7)) << 4));
        int n = wn * 64 + t * 16 + l16;
        bfr[t] = *(const i32x4*)(sB + n * 128 + ((((ks << 2) + quad) ^ (n & 7)) << 4));
      }
#pragma unroll
      for (int mt = 0; mt < 4; ++mt)
#pragma unroll
        for (int nt = 0; nt < 4; ++nt)
          acc[mt][nt] = __builtin_amdgcn_mfma_i32_16x16x64_i8(af[mt], bfr[nt], acc[mt][nt], 0, 0, 0);
    }
  }

  const float sv = sw[0] * (__uint_as_float(amax[0]) / 127.0f);
  const float sbv = bs[0];
  const int zbv = bz[0];
#pragma unroll
  for (int nt = 0; nt < 4; ++nt) {
    const int o = Nb + wn * 64 + nt * 16 + l16;
    const float bias = sbv * (float)(bq[o] - zbv);
    const int which = o >> 11;
    const int cc = o & 2047;
    const int h = cc >> 7, d = cc & 127;
#pragma unroll
    for (int mt = 0; mt < 4; ++mt) {
      const int m0 = Mb + wm * 64 + mt * 16 + quad * 4;
      const int bi = m0 >> 10, t0 = m0 & 1023;
      const size_t bhx = (size_t)bi * 16 + h;
      if (which == 2) {
        ushort4 pv;
        pv.x = f2bf((float)acc[mt][nt][0] * sv + bias);
        pv.y = f2bf((float)acc[mt][nt][1] * sv + bias);
        pv.z = f2bf((float)acc[mt][nt][2] * sv + bias);
        pv.w = f2bf((float)acc[mt][nt][3] * sv + bias);
        *(ushort4*)(vT + (bhx * 128 + d) * 1024 + t0) = pv;
      } else {
        u16* dst = (which == 0 ? qb : kb) + (bhx * 1024 + t0) * 128 + d;
#pragma unroll
        for (int r = 0; r < 4; ++r) dst[r * 128] = f2bf((float)acc[mt][nt][r] * sv + bias);
      }
    }
  }
}

// ---------------- bf16 BT GEMM (proj, verified) ----------------
__global__ __launch_bounds__(256, 2) void gemm_bt_out(
    const u16* __restrict__ A, const u16* __restrict__ B, int K, int N,
    const int* __restrict__ bq, const float* __restrict__ bs, const int* __restrict__ bz,
    float* __restrict__ out) {
  __shared__ uint8_t sA[16384];
  __shared__ uint8_t sB[16384];
  const int tid = threadIdx.x;
  const int wave = tid >> 6, lane = tid & 63;
  const int quad = lane >> 4, l16 = lane & 15;
  const int wm = wave >> 1, wn = wave & 1;
  const int Mb = blockIdx.y << 7, Nb = blockIdx.x << 7;

  const u16* ag[4];
  const u16* bg[4];
  int lo[4];
#pragma unroll
  for (int i = 0; i < 4; ++i) {
    int row = wave * 32 + i * 8 + (lane >> 3);
    int c = (lane & 7) ^ (row & 7);
    ag[i] = A + (size_t)(Mb + row) * K + c * 8;
    bg[i] = B + (size_t)(Nb + row) * K + c * 8;
    lo[i] = wave * 4096 + i * 1024 + lane * 16;
  }

  f32x4 acc[4][4] = {};

  for (int kk = 0; kk < K; kk += 64) {
    __syncthreads();
#pragma unroll
    for (int i = 0; i < 4; ++i) {
      async16(ag[i] + kk, sA + lo[i]);
      async16(bg[i] + kk, sB + lo[i]);
    }
    __syncthreads();
#pragma unroll
    for (int ks = 0; ks < 2; ++ks) {
      bf16x8 af[4], bfr[4];
#pragma unroll
      for (int t = 0; t < 4; ++t) {
        int m = wm * 64 + t * 16 + l16;
        af[t] = *(const bf16x8*)(sA + m * 128 + ((((ks << 2) + quad) ^ (m & 7)) << 4));
        int n = wn * 64 + t * 16 + l16;
        bfr[t] = *(const bf16x8*)(sB + n * 128 + ((((ks << 2) + quad) ^ (n & 7)) << 4));
      }
#pragma unroll
      for (int mt = 0; mt < 4; ++mt)
#pragma unroll
        for (int nt = 0; nt < 4; ++nt)
          acc[mt][nt] = __builtin_amdgcn_mfma_f32_16x16x32_bf16(af[mt], bfr[nt], acc[mt][nt], 0, 0, 0);
    }
  }

  const float sbv = bs[0];
  const int zbv = bz[0];
#pragma unroll
  for (int nt = 0; nt < 4; ++nt) {
    const int o = Nb + wn * 64 + nt * 16 + l16;
    const float bias = sbv * (float)(bq[o] - zbv);
#pragma unroll
    for (int mt = 0; mt < 4; ++mt) {
      const int m0 = Mb + wm * 64 + mt * 16 + quad * 4;
#pragma unroll
      for (int r = 0; r < 4; ++r)
        out[(size_t)(m0 + r) * N + o] = acc[mt][nt][r] + bias;
    }
  }
}

// ---------------- flash attention: q128 (Q regs), kv64, max-free softmax ----
// Ring-2 K/V double-buffer with counted vmcnt(8): stage tile j+1 into slot
// (j+1)&1 at top of iter j; vmcnt(8) drains exactly tile j's 8 loads
// (oldest-first); raw s_barrier publishes; compute tile j (256 MFMA + softmax
// VALU covers the in-flight loads); trailing barrier protects the slot being
// restaged next iter. LDS 80KB -> still 2 blocks/CU. Addressing/swizzles are
// byte-identical to the round-0 verified kernel; only slot offsets added.
__global__ __launch_bounds__(256, 2) void attn_fwd(
    const u16* __restrict__ qg, const u16* __restrict__ kg,
    const u16* __restrict__ vg, u16* __restrict__ yb) {
  __shared__ uint8_t smem[81920];
  // sK slot s: smem + s*16384       (64 t-rows x 256B, chunk swz ^(row&15))
  // sV slot s: smem + 32768 + s*16384 (128 d-rows x 128B, chunk swz ^(d&7))
  // sP:        smem + 65536          (128 q-rows x 128B, swz ^(row&7))
  uint8_t* sVb = smem + 32768;
  uint8_t* sP = smem + 65536;
  const int tid = threadIdx.x;
  const int wave = tid >> 6, lane = tid & 63;
  const int quad = lane >> 4, l16 = lane & 15;
  const int bh = blockIdx.x;
  const int y = blockIdx.y;
  const int qi = (y < 4) ? (7 - y) : (y - 4);
  const int qbase = qi << 7;
  const size_t base = (size_t)bh << 17;
  const u16* Q = qg + base;
  const u16* Kp = kg + base;
  const u16* Vp = vg + base;

  // stage Q tile (32KB over sK slots 0+1), pull fragments to registers
#pragma unroll
  for (int i = 0; i < 8; ++i) {
    int off = wave * 8192 + i * 1024;
    int row = (off >> 8) + quad;
    int c = l16 ^ (row & 15);
    async16(Q + (size_t)(qbase + row) * 128 + c * 8, smem + off + lane * 16);
  }
  __syncthreads();
  bf16x8 qf[2][4];
#pragma unroll
  for (int mi = 0; mi < 2; ++mi)
#pragma unroll
    for (int ks = 0; ks < 4; ++ks) {
      int m = wave * 32 + mi * 16 + l16;
      qf[mi][ks] = *(const bf16x8*)(smem + m * 256 + ((((ks << 2) + quad) ^ (m & 15)) << 4));
    }
  asm volatile("s_waitcnt lgkmcnt(0)" ::: "memory");
  __builtin_amdgcn_sched_barrier(0);
  __builtin_amdgcn_s_barrier();  // all waves done reading Q region

#define STAGEKV(TB, SL) do {                                                  \
    _Pragma("unroll")                                                         \
    for (int i_ = 0; i_ < 4; ++i_) {                                          \
      int off_ = wave * 4096 + i_ * 1024;                                     \
      int rowk_ = (off_ >> 8) + quad;                                         \
      int ck_ = l16 ^ (rowk_ & 15);                                           \
      async16(Kp + (size_t)((TB) + rowk_) * 128 + ck_ * 8,                    \
              smem + (SL) * 16384 + off_ + lane * 16);                        \
      int rowd_ = (off_ >> 7) + (lane >> 3);                                  \
      int cv_ = (lane & 7) ^ (rowd_ & 7);                                     \
      async16(Vp + (size_t)rowd_ * 1024 + (TB) + cv_ * 8,                     \
              sVb + (SL) * 16384 + off_ + lane * 16);                         \
    }                                                                         \
  } while (0)

  f32x4 accO[2][8] = {};
  float lacc[2][4] = {};  // per-lane partial row sums (max-free softmax)

  const float scale = 0.088388347648318447f;  // 1/sqrt(128)
  const int jmax = 2 * qi + 1;

  STAGEKV(0, 0);  // prologue: tile 0 -> slot 0

  for (int j = 0; j <= jmax; ++j) {
    const int tb = j << 6;
    const int jn = (j + 1 <= jmax) ? j + 1 : jmax;  // clamp keeps counts uniform
    STAGEKV(jn << 6, (j + 1) & 1);
    asm volatile("s_waitcnt vmcnt(8)" ::: "memory");  // tile j's 8 loads done
    __builtin_amdgcn_s_barrier();
    const uint8_t* sK = smem + (j & 1) * 16384;
    const uint8_t* sV = sVb + (j & 1) * 16384;

    // S = Q K^T (per wave: 32 q-rows x 64 k-cols)
    f32x4 sc[2][4] = {};
#pragma unroll
    for (int ks = 0; ks < 4; ++ks) {
      bf16x8 kf[4];
#pragma unroll
      for (int ni = 0; ni < 4; ++ni) {
        int n = ni * 16 + l16;
        kf[ni] = *(const bf16x8*)(sK + n * 256 + ((((ks << 2) + quad) ^ (n & 15)) << 4));
      }
#pragma unroll
      for (int mi = 0; mi < 2; ++mi)
#pragma unroll
        for (int ni = 0; ni < 4; ++ni)
          sc[mi][ni] = __builtin_amdgcn_mfma_f32_16x16x32_bf16(qf[mi][ks], kf[ni], sc[mi][ni], 0, 0, 0);
    }

    // max-free softmax: p = exp(s*scale); masked -> exp(-inf) = 0.
    const bool needmask = (tb + 63) > qbase;
#pragma unroll
    for (int mi = 0; mi < 2; ++mi) {
      const int row0 = qbase + wave * 32 + mi * 16 + quad * 4;
#pragma unroll
      for (int ni = 0; ni < 4; ++ni) {
        const int col = tb + ni * 16 + l16;
#pragma unroll
        for (int r = 0; r < 4; ++r) {
          float s = sc[mi][ni][r] * scale;
          if (needmask && col > row0 + r) s = -INFINITY;
          float p = __expf(s);
          sc[mi][ni][r] = p;
          lacc[mi][r] += p;
        }
      }
    }

    // P (bf16) -> sP; each wave writes (and later reads) only its own 32 rows
#pragma unroll
    for (int mi = 0; mi < 2; ++mi)
#pragma unroll
      for (int ni = 0; ni < 4; ++ni)
#pragma unroll
        for (int r = 0; r < 4; ++r) {
          int qr = wave * 32 + mi * 16 + quad * 4 + r;
          int kc = ni * 16 + l16;
          *(u16*)(sP + qr * 128 + (((kc >> 3) ^ (qr & 7)) << 4) + (kc & 7) * 2) =
              f2bf(sc[mi][ni][r]);
        }
    // no barrier: P rows are wave-private; lgkmcnt ordering suffices

    // O += P @ V
#pragma unroll
    for (int ks = 0; ks < 2; ++ks) {
      bf16x8 pf[2], vf[8];
#pragma unroll
      for (int mi = 0; mi < 2; ++mi) {
        int m = wave * 32 + mi * 16 + l16;
        pf[mi] = *(const bf16x8*)(sP + m * 128 + ((((ks << 2) + quad) ^ (m & 7)) << 4));
      }
#pragma unroll
      for (int ni = 0; ni < 8; ++ni) {
        int n = ni * 16 + l16;
        vf[ni] = *(const bf16x8*)(sV + n * 128 + ((((ks << 2) + quad) ^ (n & 7)) << 4));
      }
#pragma unroll
      for (int mi = 0; mi < 2; ++mi)
#pragma unroll
        for (int ni = 0; ni < 8; ++ni)
          accO[mi][ni] = __builtin_amdgcn_mfma_f32_16x16x32_bf16(pf[mi], vf[ni], accO[mi][ni], 0, 0, 0);
    }
    __builtin_amdgcn_s_barrier();  // all waves done reading slot j&1 before restage
  }
  asm volatile("s_waitcnt vmcnt(0)" ::: "memory");  // drain dummy prefetch

  // epilogue: reduce row sums across the 16 col-lanes, then y[b, t, h*128+d]
  const int b = bh >> 4, h = bh & 15;
#pragma unroll
  for (int mi = 0; mi < 2; ++mi) {
    float inv[4];
#pragma unroll
    for (int r = 0; r < 4; ++r) {
      float l = lacc[mi][r];
#pragma unroll
      for (int x = 1; x < 16; x <<= 1) l += __shfl_xor(l, x);
      inv[r] = 1.0f / l;
    }
#pragma unroll
    for (int ni = 0; ni < 8; ++ni)
#pragma unroll
      for (int r = 0; r < 4; ++r) {
        int row = qbase + wave * 32 + mi * 16 + quad * 4 + r;
        int col = (h << 7) + ni * 16 + l16;
        yb[((size_t)(b * 1024 + row) << 11) + col] = f2bf(accO[mi][ni][r] * inv[r]);
      }
  }
#undef STAGEKV
}

// ---------------- launch ----------------
extern "C" void kernel_launch(void* const* d_in, const int* in_sizes, int n_in,
                              void* d_out, int out_size, void* d_ws, size_t ws_size,
                              hipStream_t stream) {
  const float* x = (const float*)d_in[0];
  const int* waq = (const int*)d_in[1];
  const float* s_wa = (const float*)d_in[2];
  const int* z_wa = (const int*)d_in[3];
  const int* baq = (const int*)d_in[4];
  const float* s_ba = (const float*)d_in[5];
  const int* z_ba = (const int*)d_in[6];
  const int* wpq = (const int*)d_in[7];
  const float* s_wp = (const float*)d_in[8];
  const int* z_wp = (const int*)d_in[9];
  const int* bpq = (const int*)d_in[10];
  const float* s_bp = (const float*)d_in[11];
  const int* z_bp = (const int*)d_in[12];

  // workspace: xq[0,8) wa8[8,20) wp_bf[20,28) qb[28,44) kb[44,60) vT[60,76) yb[76,92) amax[92] MiB
  char* ws = (char*)d_ws;
  char* xq    = ws + 0;
  char* wa8   = ws + 8388608;
  u16* wp_bf  = (u16*)(ws + 20971520);
  u16* qb     = (u16*)(ws + 29360128);
  u16* kb     = (u16*)(ws + 46137344);
  u16* vT     = (u16*)(ws + 62914560);
  u16* yb     = (u16*)(ws + 79691776);
  unsigned* amax = (unsigned*)(ws + 96468992);

  hipMemsetAsync(amax, 0, 4, stream);
  absmax_x<<<1024, 256, 0, stream>>>((const float4*)x, amax, 2097152);
  quant_x<<<8192, 256, 0, stream>>>((const float4*)x, (char4*)xq, amax, 2097152);
  dequant_w8<<<12288, 256, 0, stream>>>((const int4*)waq, (char4*)wa8, 3145728, z_wa);
  dequant4<<<4096, 256, 0, stream>>>((const int4*)wpq, (ushort4*)wp_bf, 1048576, s_wp, z_wp);

  gemm_i8_qkv<<<dim3(48, 32), 256, 0, stream>>>(xq, wa8, 2048, s_wa, amax,
                                                baq, s_ba, z_ba, qb, kb, vT);

  attn_fwd<<<dim3(64, 8), 256, 0, stream>>>(qb, kb, vT, yb);

  gemm_bt_out<<<dim3(16, 32), 256, 0, stream>>>(yb, wp_bf, 2048, 2048,
                                                bpq, s_bp, z_bp, (float*)d_out);
}

// Round 5
// 289.586 us; speedup vs baseline: 1.2811x; 1.1762x over previous
//
#include <hip/hip_runtime.h>
#include <stdint.h>
#include <math.h>

typedef unsigned short u16;
typedef __attribute__((ext_vector_type(4))) float f32x4;
typedef __attribute__((ext_vector_type(4))) int i32x4;
typedef __attribute__((ext_vector_type(8))) short bf16x8;

__device__ __forceinline__ u16 f2bf(float f) {
  uint32_t u = __float_as_uint(f);
  u += 0x7FFFu + ((u >> 16) & 1u);
  return (u16)(u >> 16);
}

__device__ __forceinline__ void async16(const void* g, void* l) {
  __builtin_amdgcn_global_load_lds(
      (const __attribute__((address_space(1))) void*)g,
      (__attribute__((address_space(3))) void*)l, 16, 0, 0);
}

// ---------------- prep ----------------
// absmax: per-block max -> amax_arr[1024] (plain stores; no memset, no atomics)
__global__ void absmax_x(const float4* __restrict__ x, float* __restrict__ amax_arr, int n4) {
  __shared__ float red[4];
  int i = blockIdx.x * 256 + threadIdx.x;
  float m = 0.f;
  for (; i < n4; i += gridDim.x * 256) {
    float4 v = x[i];
    m = fmaxf(m, fmaxf(fmaxf(fabsf(v.x), fabsf(v.y)), fmaxf(fabsf(v.z), fabsf(v.w))));
  }
#pragma unroll
  for (int s = 1; s < 64; s <<= 1) m = fmaxf(m, __shfl_xor(m, s));
  if ((threadIdx.x & 63) == 0) red[threadIdx.x >> 6] = m;
  __syncthreads();
  if (threadIdx.x == 0)
    amax_arr[blockIdx.x] = fmaxf(fmaxf(red[0], red[1]), fmaxf(red[2], red[3]));
}

// fused quant_x [0,8192) + dequant_w8 [8192,20480) + dequant4 [20480,24576)
// quant blocks wave-redundantly reduce amax_arr (4KB, L2-hot) -- no barrier.
__global__ void prep_fused(
    const float4* __restrict__ x, char4* __restrict__ xq,
    const int4* __restrict__ waq, char4* __restrict__ wa8, const int* __restrict__ z_wa,
    const int4* __restrict__ wpq, ushort4* __restrict__ wp_bf,
    const float* __restrict__ s_wp, const int* __restrict__ z_wp,
    const float* __restrict__ amax_arr, float* __restrict__ amax_final) {
  const int bid = blockIdx.x;
  const int tid = threadIdx.x;
  if (bid < 8192) {
    const int lane = tid & 63;
    float m = 0.f;
#pragma unroll
    for (int k = 0; k < 4; ++k) {
      float4 a = ((const float4*)amax_arr)[lane * 4 + k];
      m = fmaxf(m, fmaxf(fmaxf(a.x, a.y), fmaxf(a.z, a.w)));
    }
#pragma unroll
    for (int s = 1; s < 64; s <<= 1) m = fmaxf(m, __shfl_xor(m, s));
    if (bid == 0 && tid == 0) amax_final[0] = m;
    const float inv = 127.0f / m;
    const int i = bid * 256 + tid;
    float4 v = x[i];
    char4 r;
    r.x = (char)__float2int_rn(v.x * inv);
    r.y = (char)__float2int_rn(v.y * inv);
    r.z = (char)__float2int_rn(v.z * inv);
    r.w = (char)__float2int_rn(v.w * inv);
    xq[i] = r;
  } else if (bid < 20480) {
    const int zv = z_wa[0];
    const int i = (bid - 8192) * 256 + tid;
    int4 v = waq[i];
    char4 r;
    r.x = (char)(v.x - zv); r.y = (char)(v.y - zv);
    r.z = (char)(v.z - zv); r.w = (char)(v.w - zv);
    wa8[i] = r;
  } else {
    const float sv = s_wp[0];
    const int zv = z_wp[0];
    const int i = (bid - 20480) * 256 + tid;
    int4 v = wpq[i];
    ushort4 r;
    r.x = f2bf(sv * (float)(v.x - zv));
    r.y = f2bf(sv * (float)(v.y - zv));
    r.z = f2bf(sv * (float)(v.z - zv));
    r.w = f2bf(sv * (float)(v.w - zv));
    wp_bf[i] = r;
  }
}

// ---------------- i8 BT GEMM (QKV, R7-verified round-0 version) ----------------
__global__ __launch_bounds__(256, 2) void gemm_i8_qkv(
    const char* __restrict__ A, const char* __restrict__ B, int K,
    const float* __restrict__ sw, const float* __restrict__ amaxf,
    const int* __restrict__ bq, const float* __restrict__ bs, const int* __restrict__ bz,
    u16* __restrict__ qb, u16* __restrict__ kb, u16* __restrict__ vT) {
  __shared__ uint8_t sA[16384];
  __shared__ uint8_t sB[16384];
  const int tid = threadIdx.x;
  const int wave = tid >> 6, lane = tid & 63;
  const int quad = lane >> 4, l16 = lane & 15;
  const int wm = wave >> 1, wn = wave & 1;
  const int Mb = blockIdx.y << 7, Nb = blockIdx.x << 7;

  const char* ag[4];
  const char* bg[4];
  int lo[4];
#pragma unroll
  for (int i = 0; i < 4; ++i) {
    int row = wave * 32 + i * 8 + (lane >> 3);
    int c = (lane & 7) ^ (row & 7);
    ag[i] = A + (size_t)(Mb + row) * K + c * 16;
    bg[i] = B + (size_t)(Nb + row) * K + c * 16;
    lo[i] = wave * 4096 + i * 1024 + lane * 16;
  }

  i32x4 acc[4][4] = {};

  for (int kk = 0; kk < K; kk += 128) {
    __syncthreads();
#pragma unroll
    for (int i = 0; i < 4; ++i) {
      async16(ag[i] + kk, sA + lo[i]);
      async16(bg[i] + kk, sB + lo[i]);
    }
    __syncthreads();
#pragma unroll
    for (int ks = 0; ks < 2; ++ks) {
      i32x4 af[4], bfr[4];
#pragma unroll
      for (int t = 0; t < 4; ++t) {
        int m = wm * 64 + t * 16 + l16;
        af[t] = *(const i32x4*)(sA + m * 128 + ((((ks << 2) + quad) ^ (m & 7)) << 4));
        int n = wn * 64 + t * 16 + l16;
        bfr[t] = *(const i32x4*)(sB + n * 128 + ((((ks << 2) + quad) ^ (n & 7)) << 4));
      }
#pragma unroll
      for (int mt = 0; mt < 4; ++mt)
#pragma unroll
        for (int nt = 0; nt < 4; ++nt)
          acc[mt][nt] = __builtin_amdgcn_mfma_i32_16x16x64_i8(af[mt], bfr[nt], acc[mt][nt], 0, 0, 0);
    }
  }

  const float sv = sw[0] * (amaxf[0] / 127.0f);
  const float sbv = bs[0];
  const int zbv = bz[0];
#pragma unroll
  for (int nt = 0; nt < 4; ++nt) {
    const int o = Nb + wn * 64 + nt * 16 + l16;
    const float bias = sbv * (float)(bq[o] - zbv);
    const int which = o >> 11;
    const int cc = o & 2047;
    const int h = cc >> 7, d = cc & 127;
#pragma unroll
    for (int mt = 0; mt < 4; ++mt) {
      const int m0 = Mb + wm * 64 + mt * 16 + quad * 4;
      const int bi = m0 >> 10, t0 = m0 & 1023;
      const size_t bhx = (size_t)bi * 16 + h;
      if (which == 2) {
        ushort4 pv;
        pv.x = f2bf((float)acc[mt][nt][0] * sv + bias);
        pv.y = f2bf((float)acc[mt][nt][1] * sv + bias);
        pv.z = f2bf((float)acc[mt][nt][2] * sv + bias);
        pv.w = f2bf((float)acc[mt][nt][3] * sv + bias);
        *(ushort4*)(vT + (bhx * 128 + d) * 1024 + t0) = pv;
      } else {
        u16* dst = (which == 0 ? qb : kb) + (bhx * 1024 + t0) * 128 + d;
#pragma unroll
        for (int r = 0; r < 4; ++r) dst[r * 128] = f2bf((float)acc[mt][nt][r] * sv + bias);
      }
    }
  }
}

// ---------------- bf16 BT GEMM (proj, verified) ----------------
__global__ __launch_bounds__(256, 2) void gemm_bt_out(
    const u16* __restrict__ A, const u16* __restrict__ B, int K, int N,
    const int* __restrict__ bq, const float* __restrict__ bs, const int* __restrict__ bz,
    float* __restrict__ out) {
  __shared__ uint8_t sA[16384];
  __shared__ uint8_t sB[16384];
  const int tid = threadIdx.x;
  const int wave = tid >> 6, lane = tid & 63;
  const int quad = lane >> 4, l16 = lane & 15;
  const int wm = wave >> 1, wn = wave & 1;
  const int Mb = blockIdx.y << 7, Nb = blockIdx.x << 7;

  const u16* ag[4];
  const u16* bg[4];
  int lo[4];
#pragma unroll
  for (int i = 0; i < 4; ++i) {
    int row = wave * 32 + i * 8 + (lane >> 3);
    int c = (lane & 7) ^ (row & 7);
    ag[i] = A + (size_t)(Mb + row) * K + c * 8;
    bg[i] = B + (size_t)(Nb + row) * K + c * 8;
    lo[i] = wave * 4096 + i * 1024 + lane * 16;
  }

  f32x4 acc[4][4] = {};

  for (int kk = 0; kk < K; kk += 64) {
    __syncthreads();
#pragma unroll
    for (int i = 0; i < 4; ++i) {
      async16(ag[i] + kk, sA + lo[i]);
      async16(bg[i] + kk, sB + lo[i]);
    }
    __syncthreads();
#pragma unroll
    for (int ks = 0; ks < 2; ++ks) {
      bf16x8 af[4], bfr[4];
#pragma unroll
      for (int t = 0; t < 4; ++t) {
        int m = wm * 64 + t * 16 + l16;
        af[t] = *(const bf16x8*)(sA + m * 128 + ((((ks << 2) + quad) ^ (m & 7)) << 4));
        int n = wn * 64 + t * 16 + l16;
        bfr[t] = *(const bf16x8*)(sB + n * 128 + ((((ks << 2) + quad) ^ (n & 7)) << 4));
      }
#pragma unroll
      for (int mt = 0; mt < 4; ++mt)
#pragma unroll
        for (int nt = 0; nt < 4; ++nt)
          acc[mt][nt] = __builtin_amdgcn_mfma_f32_16x16x32_bf16(af[mt], bfr[nt], acc[mt][nt], 0, 0, 0);
    }
  }

  const float sbv = bs[0];
  const int zbv = bz[0];
#pragma unroll
  for (int nt = 0; nt < 4; ++nt) {
    const int o = Nb + wn * 64 + nt * 16 + l16;
    const float bias = sbv * (float)(bq[o] - zbv);
#pragma unroll
    for (int mt = 0; mt < 4; ++mt) {
      const int m0 = Mb + wm * 64 + mt * 16 + quad * 4;
#pragma unroll
      for (int r = 0; r < 4; ++r)
        out[(size_t)(m0 + r) * N + o] = acc[mt][nt][r] + bias;
    }
  }
}

// ---------------- flash attention: q128 (Q regs), kv64, max-free softmax ----
// Ring-2 K/V double-buffer with counted vmcnt(8) (R4-verified).
__global__ __launch_bounds__(256, 2) void attn_fwd(
    const u16* __restrict__ qg, const u16* __restrict__ kg,
    const u16* __restrict__ vg, u16* __restrict__ yb) {
  __shared__ uint8_t smem[81920];
  uint8_t* sVb = smem + 32768;
  uint8_t* sP = smem + 65536;
  const int tid = threadIdx.x;
  const int wave = tid >> 6, lane = tid & 63;
  const int quad = lane >> 4, l16 = lane & 15;
  const int bh = blockIdx.x;
  const int y = blockIdx.y;
  const int qi = (y < 4) ? (7 - y) : (y - 4);
  const int qbase = qi << 7;
  const size_t base = (size_t)bh << 17;
  const u16* Q = qg + base;
  const u16* Kp = kg + base;
  const u16* Vp = vg + base;

#pragma unroll
  for (int i = 0; i < 8; ++i) {
    int off = wave * 8192 + i * 1024;
    int row = (off >> 8) + quad;
    int c = l16 ^ (row & 15);
    async16(Q + (size_t)(qbase + row) * 128 + c * 8, smem + off + lane * 16);
  }
  __syncthreads();
  bf16x8 qf[2][4];
#pragma unroll
  for (int mi = 0; mi < 2; ++mi)
#pragma unroll
    for (int ks = 0; ks < 4; ++ks) {
      int m = wave * 32 + mi * 16 + l16;
      qf[mi][ks] = *(const bf16x8*)(smem + m * 256 + ((((ks << 2) + quad) ^ (m & 15)) << 4));
    }
  asm volatile("s_waitcnt lgkmcnt(0)" ::: "memory");
  __builtin_amdgcn_sched_barrier(0);
  __builtin_amdgcn_s_barrier();  // all waves done reading Q region

#define STAGEKV(TB, SL) do {                                                  \
    _Pragma("unroll")                                                         \
    for (int i_ = 0; i_ < 4; ++i_) {                                          \
      int off_ = wave * 4096 + i_ * 1024;                                     \
      int rowk_ = (off_ >> 8) + quad;                                         \
      int ck_ = l16 ^ (rowk_ & 15);                                           \
      async16(Kp + (size_t)((TB) + rowk_) * 128 + ck_ * 8,                    \
              smem + (SL) * 16384 + off_ + lane * 16);                        \
      int rowd_ = (off_ >> 7) + (lane >> 3);                                  \
      int cv_ = (lane & 7) ^ (rowd_ & 7);                                     \
      async16(Vp + (size_t)rowd_ * 1024 + (TB) + cv_ * 8,                     \
              sVb + (SL) * 16384 + off_ + lane * 16);                         \
    }                                                                         \
  } while (0)

  f32x4 accO[2][8] = {};
  float lacc[2][4] = {};

  const float scale = 0.088388347648318447f;  // 1/sqrt(128)
  const int jmax = 2 * qi + 1;

  STAGEKV(0, 0);

  for (int j = 0; j <= jmax; ++j) {
    const int tb = j << 6;
    const int jn = (j + 1 <= jmax) ? j + 1 : jmax;
    STAGEKV(jn << 6, (j + 1) & 1);
    asm volatile("s_waitcnt vmcnt(8)" ::: "memory");
    __builtin_amdgcn_s_barrier();
    const uint8_t* sK = smem + (j & 1) * 16384;
    const uint8_t* sV = sVb + (j & 1) * 16384;

    f32x4 sc[2][4] = {};
#pragma unroll
    for (int ks = 0; ks < 4; ++ks) {
      bf16x8 kf[4];
#pragma unroll
      for (int ni = 0; ni < 4; ++ni) {
        int n = ni * 16 + l16;
        kf[ni] = *(const bf16x8*)(sK + n * 256 + ((((ks << 2) + quad) ^ (n & 15)) << 4));
      }
#pragma unroll
      for (int mi = 0; mi < 2; ++mi)
#pragma unroll
        for (int ni = 0; ni < 4; ++ni)
          sc[mi][ni] = __builtin_amdgcn_mfma_f32_16x16x32_bf16(qf[mi][ks], kf[ni], sc[mi][ni], 0, 0, 0);
    }

    const bool needmask = (tb + 63) > qbase;
#pragma unroll
    for (int mi = 0; mi < 2; ++mi) {
      const int row0 = qbase + wave * 32 + mi * 16 + quad * 4;
#pragma unroll
      for (int ni = 0; ni < 4; ++ni) {
        const int col = tb + ni * 16 + l16;
#pragma unroll
        for (int r = 0; r < 4; ++r) {
          float s = sc[mi][ni][r] * scale;
          if (needmask && col > row0 + r) s = -INFINITY;
          float p = __expf(s);
          sc[mi][ni][r] = p;
          lacc[mi][r] += p;
        }
      }
    }

#pragma unroll
    for (int mi = 0; mi < 2; ++mi)
#pragma unroll
      for (int ni = 0; ni < 4; ++ni)
#pragma unroll
        for (int r = 0; r < 4; ++r) {
          int qr = wave * 32 + mi * 16 + quad * 4 + r;
          int kc = ni * 16 + l16;
          *(u16*)(sP + qr * 128 + (((kc >> 3) ^ (qr & 7)) << 4) + (kc & 7) * 2) =
              f2bf(sc[mi][ni][r]);
        }

#pragma unroll
    for (int ks = 0; ks < 2; ++ks) {
      bf16x8 pf[2], vf[8];
#pragma unroll
      for (int mi = 0; mi < 2; ++mi) {
        int m = wave * 32 + mi * 16 + l16;
        pf[mi] = *(const bf16x8*)(sP + m * 128 + ((((ks << 2) + quad) ^ (m & 7)) << 4));
      }
#pragma unroll
      for (int ni = 0; ni < 8; ++ni) {
        int n = ni * 16 + l16;
        vf[ni] = *(const bf16x8*)(sV + n * 128 + ((((ks << 2) + quad) ^ (n & 7)) << 4));
      }
#pragma unroll
      for (int mi = 0; mi < 2; ++mi)
#pragma unroll
        for (int ni = 0; ni < 8; ++ni)
          accO[mi][ni] = __builtin_amdgcn_mfma_f32_16x16x32_bf16(pf[mi], vf[ni], accO[mi][ni], 0, 0, 0);
    }
    __builtin_amdgcn_s_barrier();
  }
  asm volatile("s_waitcnt vmcnt(0)" ::: "memory");

  const int b = bh >> 4, h = bh & 15;
#pragma unroll
  for (int mi = 0; mi < 2; ++mi) {
    float inv[4];
#pragma unroll
    for (int r = 0; r < 4; ++r) {
      float l = lacc[mi][r];
#pragma unroll
      for (int x = 1; x < 16; x <<= 1) l += __shfl_xor(l, x);
      inv[r] = 1.0f / l;
    }
#pragma unroll
    for (int ni = 0; ni < 8; ++ni)
#pragma unroll
      for (int r = 0; r < 4; ++r) {
        int row = qbase + wave * 32 + mi * 16 + quad * 4 + r;
        int col = (h << 7) + ni * 16 + l16;
        yb[((size_t)(b * 1024 + row) << 11) + col] = f2bf(accO[mi][ni][r] * inv[r]);
      }
  }
#undef STAGEKV
}

// ---------------- launch ----------------
extern "C" void kernel_launch(void* const* d_in, const int* in_sizes, int n_in,
                              void* d_out, int out_size, void* d_ws, size_t ws_size,
                              hipStream_t stream) {
  const float* x = (const float*)d_in[0];
  const int* waq = (const int*)d_in[1];
  const float* s_wa = (const float*)d_in[2];
  const int* z_wa = (const int*)d_in[3];
  const int* baq = (const int*)d_in[4];
  const float* s_ba = (const float*)d_in[5];
  const int* z_ba = (const int*)d_in[6];
  const int* wpq = (const int*)d_in[7];
  const float* s_wp = (const float*)d_in[8];
  const int* z_wp = (const int*)d_in[9];
  const int* bpq = (const int*)d_in[10];
  const float* s_bp = (const float*)d_in[11];
  const int* z_bp = (const int*)d_in[12];

  // workspace: xq[0,8) wa8[8,20) wp_bf[20,28) qb[28,44) kb[44,60) vT[60,76)
  // yb[76,92) MiB; amax_arr @92MiB (4KB); amax_final after it
  char* ws = (char*)d_ws;
  char* xq    = ws + 0;
  char* wa8   = ws + 8388608;
  u16* wp_bf  = (u16*)(ws + 20971520);
  u16* qb     = (u16*)(ws + 29360128);
  u16* kb     = (u16*)(ws + 46137344);
  u16* vT     = (u16*)(ws + 62914560);
  u16* yb     = (u16*)(ws + 79691776);
  float* amax_arr   = (float*)(ws + 96468992);
  float* amax_final = (float*)(ws + 96473088);

  absmax_x<<<1024, 256, 0, stream>>>((const float4*)x, amax_arr, 2097152);
  prep_fused<<<24576, 256, 0, stream>>>(
      (const float4*)x, (char4*)xq,
      (const int4*)waq, (char4*)wa8, z_wa,
      (const int4*)wpq, (ushort4*)wp_bf, s_wp, z_wp,
      amax_arr, amax_final);

  gemm_i8_qkv<<<dim3(48, 32), 256, 0, stream>>>(xq, wa8, 2048, s_wa, amax_final,
                                                baq, s_ba, z_ba, qb, kb, vT);

  attn_fwd<<<dim3(64, 8), 256, 0, stream>>>(qb, kb, vT, yb);

  gemm_bt_out<<<dim3(16, 32), 256, 0, stream>>>(yb, wp_bf, 2048, 2048,
                                                bpq, s_bp, z_bp, (float*)d_out);
}